// Round 1
// baseline (207.145 us; speedup 1.0000x reference)
//
#include <hip/hip_runtime.h>
#include <hip/hip_bf16.h>

// ---------------------------------------------------------------------------
// Pipeline:
//  gemm_f32 (split-K, partials) x3  -> reduce_ep (sum + bias + lrelu) x3
//  gemm4_mfma (bf16 MFMA, T fp32->bf16 in LDS, K-split 2) -> accM[2][128][10240]
//  pairwise (per-o block: 128x20 tile in LDS, 4-j register blocking)
//  final_dot (feat[128][1536] @ Wc + bc)
// ws layout (bytes):
//   [0, 10485760)           P (gemm partials, <=8MB)  /  accM (2*5.24MB)  (lifetimes disjoint)
//   [10485760, 11534336)    h1   128x2048 f32
//   [11534336, 12058624)    h2   128x1024 f32
//   [12058624, 12320768)    h3b  128x1024 bf16
//   [12320768, 13107200)    feat 128x1536 f32  ( [h3 | o_b] )
// ---------------------------------------------------------------------------

typedef __bf16 bf16x8 __attribute__((ext_vector_type(8)));
typedef float  f32x4  __attribute__((ext_vector_type(4)));

static __device__ __forceinline__ unsigned int f2bf(float f) {
  union { float f; unsigned int u; } v; v.f = f;
  unsigned int r = v.u + 0x7FFFu + ((v.u >> 16) & 1u);   // RNE to bf16
  return r >> 16;
}

static __device__ __forceinline__ float lrelu(float x) {
  return x >= 0.0f ? x : 0.01f * x;
}

static __device__ __forceinline__ void fma4(float4& c, float a, const float4& w) {
  c.x = fmaf(a, w.x, c.x); c.y = fmaf(a, w.y, c.y);
  c.z = fmaf(a, w.z, c.z); c.w = fmaf(a, w.w, c.w);
}

// ---------------------------------------------------------------------------
// fp32 GEMM, split-K into partial buffers.
// Block: 256 thr, tile = 128 rows x 32 cols, micro-tile 4 rows x 4 cols.
// Grid: (N/32, S). Writes P[s][128][N].
// ---------------------------------------------------------------------------
__global__ __launch_bounds__(256, 2) void gemm_f32(
    const float* __restrict__ A, const float* __restrict__ W,
    float* __restrict__ P, int lda, int N, int kchunk)
{
  __shared__ __align__(16) float As[16 * 128];   // [k][row], transposed
  __shared__ __align__(16) float Ws[16 * 32];    // [k][col]
  const int t     = threadIdx.x;
  const int c0    = blockIdx.x * 32;
  const int kbase = blockIdx.y * kchunk;
  const int rowg  = t >> 3;          // 0..31 -> rows rowg*4..+3
  const int colg  = t & 7;           // 0..7  -> cols colg*4..+3

  float4 acc[4];
  acc[0] = make_float4(0, 0, 0, 0); acc[1] = make_float4(0, 0, 0, 0);
  acc[2] = make_float4(0, 0, 0, 0); acc[3] = make_float4(0, 0, 0, 0);

  for (int kt = 0; kt < kchunk; kt += 16) {
    const int k0 = kbase + kt;
    { // stage A[128][16] transposed into As[k][r]
      int r = t >> 1, kh = (t & 1) * 8;
      const float* ap = A + (size_t)r * lda + k0 + kh;
      float4 a0 = *(const float4*)ap;
      float4 a1 = *(const float4*)(ap + 4);
      As[(kh + 0) * 128 + r] = a0.x; As[(kh + 1) * 128 + r] = a0.y;
      As[(kh + 2) * 128 + r] = a0.z; As[(kh + 3) * 128 + r] = a0.w;
      As[(kh + 4) * 128 + r] = a1.x; As[(kh + 5) * 128 + r] = a1.y;
      As[(kh + 6) * 128 + r] = a1.z; As[(kh + 7) * 128 + r] = a1.w;
    }
    { // stage W[16][32]
      int kw = t >> 4, f = t & 15;
      float2 w = *(const float2*)(W + (size_t)(k0 + kw) * N + c0 + f * 2);
      *(float2*)(Ws + kw * 32 + f * 2) = w;
    }
    __syncthreads();
    #pragma unroll
    for (int k = 0; k < 16; k++) {
      float4 w = *(const float4*)(Ws + k * 32 + colg * 4);
      float4 a = *(const float4*)(As + k * 128 + rowg * 4);
      fma4(acc[0], a.x, w); fma4(acc[1], a.y, w);
      fma4(acc[2], a.z, w); fma4(acc[3], a.w, w);
    }
    __syncthreads();
  }

  float* op = P + (size_t)blockIdx.y * 128 * N + (size_t)(rowg * 4) * N + c0 + colg * 4;
  *(float4*)op            = acc[0];
  *(float4*)(op + N)      = acc[1];
  *(float4*)(op + 2 * N)  = acc[2];
  *(float4*)(op + 3 * N)  = acc[3];
}

// ---------------------------------------------------------------------------
// Sum S partials + bias + LeakyReLU. Optional bf16 copy (for h3 -> gemm4).
// grid = 128*N/4/256 blocks, one float4 per thread.
// ---------------------------------------------------------------------------
__global__ __launch_bounds__(256) void reduce_ep(
    const float* __restrict__ P, const float* __restrict__ bias,
    float* __restrict__ outF, unsigned short* __restrict__ outB,
    int N, int S, int ldo)
{
  const int gid = blockIdx.x * 256 + threadIdx.x;
  const int c4  = N >> 2;
  const int r   = gid / c4;
  const int c   = (gid - r * c4) * 4;
  float4 s = make_float4(0, 0, 0, 0);
  for (int si = 0; si < S; si++) {
    float4 p = *(const float4*)(P + (size_t)si * 128 * N + (size_t)r * N + c);
    s.x += p.x; s.y += p.y; s.z += p.z; s.w += p.w;
  }
  float4 b = *(const float4*)(bias + c);
  s.x = lrelu(s.x + b.x); s.y = lrelu(s.y + b.y);
  s.z = lrelu(s.z + b.z); s.w = lrelu(s.w + b.w);
  *(float4*)(outF + (size_t)r * ldo + c) = s;
  if (outB) {
    ushort4 u;
    u.x = (unsigned short)f2bf(s.x); u.y = (unsigned short)f2bf(s.y);
    u.z = (unsigned short)f2bf(s.z); u.w = (unsigned short)f2bf(s.w);
    *(ushort4*)(outB + (size_t)r * N + c) = u;
  }
}

// ---------------------------------------------------------------------------
// gemm4: M = h3(bf16) @ T(fp32->bf16), MFMA 16x16x32.
// Block: 256 thr (4 waves), tile 128 rows x 64 cols, Kt=32, K-chunk 512.
// Grid: (160, 2). Wave w: rows w*32..+31 (2 m-tiles) x 4 n-tiles.
// T staged transposed as packed bf16 k-pairs: Wst[n][kp] dwords, row stride 20.
// ---------------------------------------------------------------------------
__global__ __launch_bounds__(256, 2) void gemm4_mfma(
    const unsigned short* __restrict__ h3b, const float* __restrict__ T,
    float* __restrict__ accM)
{
  __shared__ __align__(16) unsigned short Asm[128 * 32]; // [row][k] bf16
  __shared__ __align__(16) unsigned int   Wst[64 * 20];  // [n][kpair], stride 20 dwords
  const int t     = threadIdx.x;
  const int c0    = blockIdx.x * 64;
  const int kbase = blockIdx.y * 512;
  const int lane  = t & 63, wave = t >> 6;
  const int ml    = lane & 15, q = lane >> 4;
  const int r0    = wave * 32;

  f32x4 acc[2][4];
  #pragma unroll
  for (int i = 0; i < 2; i++)
    #pragma unroll
    for (int j = 0; j < 4; j++) acc[i][j] = (f32x4){0.f, 0.f, 0.f, 0.f};

  for (int kt = 0; kt < 16; kt++) {
    const int k0 = kbase + kt * 32;
    { // stage A: 128x32 bf16 (already bf16 in global; straight copy)
      int r = t >> 2, qq = t & 3;
      uint4 v0 = *(const uint4*)(h3b + (size_t)r * 1024 + k0 + qq * 8);
      uint4 v1 = *(const uint4*)(h3b + (size_t)(r + 64) * 1024 + k0 + qq * 8);
      *(uint4*)(Asm + r * 32 + qq * 8)        = v0;
      *(uint4*)(Asm + (r + 64) * 32 + qq * 8) = v1;
    }
    { // stage T: 32k x 64n, convert + transpose: pack (k=2kp, 2kp+1) pairs per dword
      int kp = t >> 4, n4 = (t & 15) * 4;
      const float* w0 = T + (size_t)(k0 + 2 * kp) * 10240 + c0 + n4;
      float4 wa = *(const float4*)w0;
      float4 wb = *(const float4*)(w0 + 10240);
      Wst[(n4 + 0) * 20 + kp] = f2bf(wa.x) | (f2bf(wb.x) << 16);
      Wst[(n4 + 1) * 20 + kp] = f2bf(wa.y) | (f2bf(wb.y) << 16);
      Wst[(n4 + 2) * 20 + kp] = f2bf(wa.z) | (f2bf(wb.z) << 16);
      Wst[(n4 + 3) * 20 + kp] = f2bf(wa.w) | (f2bf(wb.w) << 16);
    }
    __syncthreads();
    // A frags: A[m = tile+ml][k = q*8+j] -> contiguous 16B in Asm
    bf16x8 a0 = *(const bf16x8*)(Asm + (r0 + ml) * 32 + q * 8);
    bf16x8 a1 = *(const bf16x8*)(Asm + (r0 + 16 + ml) * 32 + q * 8);
    #pragma unroll
    for (int ct = 0; ct < 4; ct++) {
      // B frag: B[k = q*8+j][n = ct*16+ml] -> dwords q*4.. of row n
      bf16x8 b = *(const bf16x8*)((const unsigned short*)Wst +
                                  (size_t)((ct * 16 + ml) * 20 + q * 4) * 2);
      acc[0][ct] = __builtin_amdgcn_mfma_f32_16x16x32_bf16(a0, b, acc[0][ct], 0, 0, 0);
      acc[1][ct] = __builtin_amdgcn_mfma_f32_16x16x32_bf16(a1, b, acc[1][ct], 0, 0, 0);
    }
    __syncthreads();
  }

  // C/D layout: col = lane&15, row = (lane>>4)*4 + reg
  float* out = accM + (size_t)blockIdx.y * 128 * 10240;
  #pragma unroll
  for (int rt = 0; rt < 2; rt++)
    #pragma unroll
    for (int ct = 0; ct < 4; ct++) {
      int col = c0 + ct * 16 + ml;
      int row = r0 + rt * 16 + q * 4;
      #pragma unroll
      for (int i = 0; i < 4; i++)
        out[(size_t)(row + i) * 10240 + col] = acc[rt][ct][i];
    }
}

// ---------------------------------------------------------------------------
// pairwise: one block per o (512 blocks).
// o_b[j] = sum_i exp(-sum_k |M[i,o,k]-M[j,o,k]|) - 1; M = accM[0]+accM[1].
// Thread: 4 j-columns in regs, 16-i strip; float4 broadcast reads of Mi.
// ---------------------------------------------------------------------------
__global__ __launch_bounds__(256) void pairwise(
    const float* __restrict__ accM, float* __restrict__ feat)
{
  __shared__ __align__(16) float Ml[128 * 20];
  __shared__ float parts[8 * 128];
  const int t = threadIdx.x;
  const int o = blockIdx.x;
  { // load + combine K-splits: M[:, o, :]
    int i = t >> 1, kh = (t & 1) * 10;
    const float* p0 = accM + (size_t)i * 10240 + o * 20 + kh;
    const float* p1 = p0 + (size_t)128 * 10240;
    #pragma unroll
    for (int k = 0; k < 10; k++) Ml[i * 20 + kh + k] = p0[k] + p1[k];
  }
  __syncthreads();

  const int jg = t & 31, ihalf = t >> 5;
  float mj[4][20];
  #pragma unroll
  for (int c = 0; c < 4; c++) {
    const float* src = Ml + (size_t)(jg * 4 + c) * 20;
    #pragma unroll
    for (int k = 0; k < 20; k++) mj[c][k] = src[k];
  }
  float acc[4] = {0.f, 0.f, 0.f, 0.f};
  for (int ii = 0; ii < 16; ii++) {
    int i = ihalf * 16 + ii;
    const float4* m4 = (const float4*)(Ml + (size_t)i * 20);
    float mi[20];
    *(float4*)(mi + 0)  = m4[0]; *(float4*)(mi + 4)  = m4[1];
    *(float4*)(mi + 8)  = m4[2]; *(float4*)(mi + 12) = m4[3];
    *(float4*)(mi + 16) = m4[4];
    #pragma unroll
    for (int c = 0; c < 4; c++) {
      float norm = 0.f;
      #pragma unroll
      for (int k = 0; k < 20; k++) norm += fabsf(mi[k] - mj[c][k]);
      acc[c] += __expf(-norm);
    }
  }
  #pragma unroll
  for (int c = 0; c < 4; c++) parts[ihalf * 128 + jg * 4 + c] = acc[c];
  __syncthreads();
  if (t < 128) {
    float s = 0.f;
    #pragma unroll
    for (int ih = 0; ih < 8; ih++) s += parts[ih * 128 + t];
    feat[(size_t)t * 1536 + 1024 + o] = s - 1.0f;   // subtract self-term
  }
}

// ---------------------------------------------------------------------------
// final: out[r] = feat[r,:] . Wc + bc  (one block per row)
// ---------------------------------------------------------------------------
__global__ __launch_bounds__(256) void final_dot(
    const float* __restrict__ feat, const float* __restrict__ Wc,
    const float* __restrict__ bc, float* __restrict__ out)
{
  __shared__ float red[4];
  const int t = threadIdx.x, r = blockIdx.x;
  float s = 0.f;
  for (int c = t; c < 1536; c += 256) s += feat[(size_t)r * 1536 + c] * Wc[c];
  for (int off = 32; off > 0; off >>= 1) s += __shfl_down(s, off);
  if ((t & 63) == 0) red[t >> 6] = s;
  __syncthreads();
  if (t == 0) out[r] = red[0] + red[1] + red[2] + red[3] + bc[0];
}

// ---------------------------------------------------------------------------
extern "C" void kernel_launch(void* const* d_in, const int* in_sizes, int n_in,
                              void* d_out, int out_size, void* d_ws, size_t ws_size,
                              hipStream_t stream)
{
  const float* X  = (const float*)d_in[0];
  const float* W1 = (const float*)d_in[1];
  const float* b1 = (const float*)d_in[2];
  const float* W2 = (const float*)d_in[3];
  const float* b2 = (const float*)d_in[4];
  const float* W3 = (const float*)d_in[5];
  const float* b3 = (const float*)d_in[6];
  const float* T  = (const float*)d_in[7];
  const float* Wc = (const float*)d_in[8];
  const float* bc = (const float*)d_in[9];

  char* ws = (char*)d_ws;
  float*          P    = (float*)ws;                  // partials (<= 8MB)
  float*          accM = (float*)ws;                  // 2 x 128 x 10240 f32 (after ep3)
  float*          h1   = (float*)(ws + 10485760);
  float*          h2   = (float*)(ws + 11534336);
  unsigned short* h3b  = (unsigned short*)(ws + 12058624);
  float*          feat = (float*)(ws + 12320768);
  float*          out  = (float*)d_out;

  // layer 1: [128,2048] = lrelu(X @ W1 + b1)   K=2048, S=8
  gemm_f32<<<dim3(64, 8), 256, 0, stream>>>(X, W1, P, 2048, 2048, 256);
  reduce_ep<<<256, 256, 0, stream>>>(P, b1, h1, nullptr, 2048, 8, 2048);
  // layer 2: [128,1024] = lrelu(h1 @ W2 + b2)  K=2048, S=16
  gemm_f32<<<dim3(32, 16), 256, 0, stream>>>(h1, W2, P, 2048, 1024, 128);
  reduce_ep<<<128, 256, 0, stream>>>(P, b2, h2, nullptr, 1024, 16, 1024);
  // layer 3: [128,1024] = lrelu(h2 @ W3 + b3)  K=1024, S=8 -> feat[:, :1024] + bf16
  gemm_f32<<<dim3(32, 8), 256, 0, stream>>>(h2, W3, P, 1024, 1024, 128);
  reduce_ep<<<128, 256, 0, stream>>>(P, b3, feat, h3b, 1024, 8, 1536);
  // M = h3 @ T  (bf16 MFMA, K-split 2 into accM[0/1])
  gemm4_mfma<<<dim3(160, 2), 256, 0, stream>>>(h3b, T, accM);
  // minibatch discrimination -> feat[:, 1024:]
  pairwise<<<512, 256, 0, stream>>>(accM, feat);
  // out = feat @ Wc + bc
  final_dot<<<128, 256, 0, stream>>>(feat, Wc, bc, out);
}

// Round 2
// 193.542 us; speedup vs baseline: 1.0703x; 1.0703x over previous
//
#include <hip/hip_runtime.h>
#include <hip/hip_bf16.h>

// ---------------------------------------------------------------------------
// Pipeline:
//  gemm_f32 (split-K, reg-double-buffered, 4 blk/CU) x3 -> reduce_ep x3
//  gemm4_mfma (bf16 MFMA, K-split 4, bf16 accM, padded LDS) -> accM[4][128][10240] bf16
//  pairwise (512 thr, 2-j register blocking) -> feat[:,1024:]
//  final_dot
// ws layout (bytes):
//   [0, 10485760)          P (fp32 gemm partials, <=8.4MB)  /  accM bf16 4x128x10240
//   [10485760, 11534336)   h1   128x2048 f32
//   [11534336, 12058624)   h2   128x1024 f32
//   [12058624, 12320768)   h3b  128x1024 bf16
//   [12320768, 13107200)   feat 128x1536 f32  ( [h3 | o_b] )
// ---------------------------------------------------------------------------

typedef __bf16 bf16x8 __attribute__((ext_vector_type(8)));
typedef float  f32x4  __attribute__((ext_vector_type(4)));

static __device__ __forceinline__ unsigned int f2bf(float f) {
  union { float f; unsigned int u; } v; v.f = f;
  unsigned int r = v.u + 0x7FFFu + ((v.u >> 16) & 1u);   // RNE to bf16
  return r >> 16;
}
static __device__ __forceinline__ float bf2f(unsigned short u) {
  union { unsigned int u; float f; } v; v.u = ((unsigned int)u) << 16;
  return v.f;
}
static __device__ __forceinline__ float lrelu(float x) {
  return x >= 0.0f ? x : 0.01f * x;
}
static __device__ __forceinline__ void fma4(float4& c, float a, const float4& w) {
  c.x = fmaf(a, w.x, c.x); c.y = fmaf(a, w.y, c.y);
  c.z = fmaf(a, w.z, c.z); c.w = fmaf(a, w.w, c.w);
}

// ---------------------------------------------------------------------------
// fp32 GEMM, split-K, register-prefetch double buffering.
// Block: 256 thr, tile = 128 rows x 32 cols, micro 4x4. Grid (N/32, S).
// ---------------------------------------------------------------------------
__global__ __launch_bounds__(256, 4) void gemm_f32(
    const float* __restrict__ A, const float* __restrict__ W,
    float* __restrict__ P, int lda, int N, int kchunk)
{
  __shared__ __align__(16) float As[16 * 128];   // [k][row]
  __shared__ __align__(16) float Ws[16 * 32];    // [k][col]
  const int t     = threadIdx.x;
  const int c0    = blockIdx.x * 32;
  const int kbase = blockIdx.y * kchunk;
  const int rowg  = t >> 3;              // 0..31
  const int colg  = t & 7;               // 0..7
  const int r_s   = t >> 1, kh_s = (t & 1) * 8;
  const int kw_s  = t >> 4, f_s  = (t & 15) * 2;

  float4 acc[4];
  acc[0] = make_float4(0, 0, 0, 0); acc[1] = make_float4(0, 0, 0, 0);
  acc[2] = make_float4(0, 0, 0, 0); acc[3] = make_float4(0, 0, 0, 0);

  const float* aptr = A + (size_t)r_s * lda + kbase + kh_s;
  const float* wptr = W + (size_t)(kbase + kw_s) * N + c0 + f_s;
  float4 pa0 = *(const float4*)aptr;
  float4 pa1 = *(const float4*)(aptr + 4);
  float2 pw  = *(const float2*)wptr;

  for (int kt = 0; kt < kchunk; kt += 16) {
    As[(kh_s + 0) * 128 + r_s] = pa0.x; As[(kh_s + 1) * 128 + r_s] = pa0.y;
    As[(kh_s + 2) * 128 + r_s] = pa0.z; As[(kh_s + 3) * 128 + r_s] = pa0.w;
    As[(kh_s + 4) * 128 + r_s] = pa1.x; As[(kh_s + 5) * 128 + r_s] = pa1.y;
    As[(kh_s + 6) * 128 + r_s] = pa1.z; As[(kh_s + 7) * 128 + r_s] = pa1.w;
    *(float2*)(Ws + kw_s * 32 + f_s) = pw;
    __syncthreads();
    if (kt + 16 < kchunk) {              // prefetch next tile into regs
      aptr += 16;
      wptr += (size_t)16 * N;
      pa0 = *(const float4*)aptr;
      pa1 = *(const float4*)(aptr + 4);
      pw  = *(const float2*)wptr;
    }
    #pragma unroll
    for (int k = 0; k < 16; k++) {
      float4 w = *(const float4*)(Ws + k * 32 + colg * 4);
      float4 a = *(const float4*)(As + k * 128 + rowg * 4);
      fma4(acc[0], a.x, w); fma4(acc[1], a.y, w);
      fma4(acc[2], a.z, w); fma4(acc[3], a.w, w);
    }
    __syncthreads();
  }

  float* op = P + (size_t)blockIdx.y * 128 * N + (size_t)(rowg * 4) * N + c0 + colg * 4;
  *(float4*)op           = acc[0];
  *(float4*)(op + N)     = acc[1];
  *(float4*)(op + 2 * N) = acc[2];
  *(float4*)(op + 3 * N) = acc[3];
}

// ---------------------------------------------------------------------------
// Sum S partials + bias + LeakyReLU (+ optional bf16 copy). 128-thr blocks.
// ---------------------------------------------------------------------------
__global__ __launch_bounds__(128) void reduce_ep(
    const float* __restrict__ P, const float* __restrict__ bias,
    float* __restrict__ outF, unsigned short* __restrict__ outB,
    int N, int S, int ldo)
{
  const int gid = blockIdx.x * 128 + threadIdx.x;
  const int c4  = N >> 2;
  const int r   = gid / c4;
  const int c   = (gid - r * c4) * 4;
  float4 s = make_float4(0, 0, 0, 0);
  for (int si = 0; si < S; si++) {
    float4 p = *(const float4*)(P + (size_t)si * 128 * N + (size_t)r * N + c);
    s.x += p.x; s.y += p.y; s.z += p.z; s.w += p.w;
  }
  float4 b = *(const float4*)(bias + c);
  s.x = lrelu(s.x + b.x); s.y = lrelu(s.y + b.y);
  s.z = lrelu(s.z + b.z); s.w = lrelu(s.w + b.w);
  *(float4*)(outF + (size_t)r * ldo + c) = s;
  if (outB) {
    ushort4 u;
    u.x = (unsigned short)f2bf(s.x); u.y = (unsigned short)f2bf(s.y);
    u.z = (unsigned short)f2bf(s.z); u.w = (unsigned short)f2bf(s.w);
    *(ushort4*)(outB + (size_t)r * N + c) = u;
  }
}

// ---------------------------------------------------------------------------
// gemm4: M = h3(bf16) @ T(fp32->bf16), MFMA 16x16x32, K-split 4.
// Block: 256 thr, tile 128 x 64, 8 k-tiles of 32. Grid (160, 4).
// Asm padded to stride 40 ushorts (kills 8-way bank conflict on A-frag reads).
// Output accM: bf16[4][128][10240] (precision irrelevant: exp(-norm) ~ e^-100s).
// ---------------------------------------------------------------------------
__global__ __launch_bounds__(256, 4) void gemm4_mfma(
    const unsigned short* __restrict__ h3b, const float* __restrict__ T,
    unsigned short* __restrict__ accM)
{
  __shared__ __align__(16) unsigned short Asm[128 * 40]; // [row][k] bf16, padded
  __shared__ __align__(16) unsigned int   Wst[64 * 20];  // [n][kpair]
  const int t     = threadIdx.x;
  const int c0    = blockIdx.x * 64;
  const int kbase = blockIdx.y * 256;
  const int lane  = t & 63, wave = t >> 6;
  const int ml    = lane & 15, q = lane >> 4;
  const int r0    = wave * 32;
  const int ra = t >> 2, qa = t & 3;            // A staging
  const int kp = t & 15, n4 = (t >> 4) * 4;     // T staging

  f32x4 acc[2][4];
  #pragma unroll
  for (int i = 0; i < 2; i++)
    #pragma unroll
    for (int j = 0; j < 4; j++) acc[i][j] = (f32x4){0.f, 0.f, 0.f, 0.f};

  const unsigned short* ap = h3b + (size_t)ra * 1024 + kbase + qa * 8;
  const float*          tp = T + (size_t)(kbase + 2 * kp) * 10240 + c0 + n4;
  uint4  va0 = *(const uint4*)ap;
  uint4  va1 = *(const uint4*)(ap + 64 * 1024);
  float4 vw0 = *(const float4*)tp;
  float4 vw1 = *(const float4*)(tp + 10240);

  for (int kt = 0; kt < 8; kt++) {
    *(uint4*)(Asm + ra * 40 + qa * 8)        = va0;
    *(uint4*)(Asm + (ra + 64) * 40 + qa * 8) = va1;
    Wst[(n4 + 0) * 20 + kp] = f2bf(vw0.x) | (f2bf(vw1.x) << 16);
    Wst[(n4 + 1) * 20 + kp] = f2bf(vw0.y) | (f2bf(vw1.y) << 16);
    Wst[(n4 + 2) * 20 + kp] = f2bf(vw0.z) | (f2bf(vw1.z) << 16);
    Wst[(n4 + 3) * 20 + kp] = f2bf(vw0.w) | (f2bf(vw1.w) << 16);
    __syncthreads();
    if (kt < 7) {                               // prefetch next k-tile
      ap += 32;
      tp += (size_t)32 * 10240;
      va0 = *(const uint4*)ap;
      va1 = *(const uint4*)(ap + 64 * 1024);
      vw0 = *(const float4*)tp;
      vw1 = *(const float4*)(tp + 10240);
    }
    bf16x8 a0 = *(const bf16x8*)(Asm + (r0 + ml) * 40 + q * 8);
    bf16x8 a1 = *(const bf16x8*)(Asm + (r0 + 16 + ml) * 40 + q * 8);
    #pragma unroll
    for (int ct = 0; ct < 4; ct++) {
      bf16x8 b = *(const bf16x8*)((const unsigned short*)Wst +
                                  (size_t)((ct * 16 + ml) * 20 + q * 4) * 2);
      acc[0][ct] = __builtin_amdgcn_mfma_f32_16x16x32_bf16(a0, b, acc[0][ct], 0, 0, 0);
      acc[1][ct] = __builtin_amdgcn_mfma_f32_16x16x32_bf16(a1, b, acc[1][ct], 0, 0, 0);
    }
    __syncthreads();
  }

  // C/D layout: col = lane&15, row = (lane>>4)*4 + reg
  unsigned short* out = accM + (size_t)blockIdx.y * 128 * 10240;
  #pragma unroll
  for (int rt = 0; rt < 2; rt++)
    #pragma unroll
    for (int ct = 0; ct < 4; ct++) {
      int col = c0 + ct * 16 + ml;
      int row = r0 + rt * 16 + q * 4;
      #pragma unroll
      for (int i = 0; i < 4; i++)
        out[(size_t)(row + i) * 10240 + col] = (unsigned short)f2bf(acc[rt][ct][i]);
    }
}

// ---------------------------------------------------------------------------
// pairwise: one block per o (512 blocks x 512 thr = 4 waves/SIMD).
// o_b[j] = sum_i exp(-sum_k |M[i,o,k]-M[j,o,k]|) - 1; M = sum of 4 bf16 splits.
// Thread: 2 j-columns in regs, 16-i strip.
// ---------------------------------------------------------------------------
__global__ __launch_bounds__(512, 4) void pairwise(
    const unsigned short* __restrict__ accM, float* __restrict__ feat)
{
  __shared__ __align__(16) float Ml[128 * 20];
  __shared__ float parts[8 * 128];
  const int t = threadIdx.x;
  const int o = blockIdx.x;
  { // load + combine 4 K-splits: M[:, o, :]
    int i = t >> 2, kh = (t & 3) * 5;
    const unsigned short* p = accM + (size_t)i * 10240 + o * 20 + kh;
    #pragma unroll
    for (int k = 0; k < 5; k++) {
      float s = bf2f(p[k]) + bf2f(p[1310720 + k]) +
                bf2f(p[2621440 + k]) + bf2f(p[3932160 + k]);
      Ml[i * 20 + kh + k] = s;
    }
  }
  __syncthreads();

  const int jg = t & 63, ihalf = t >> 6;   // 64 j-groups x 8 i-strips
  float mj[2][20];
  #pragma unroll
  for (int c = 0; c < 2; c++) {
    const float* src = Ml + (size_t)(jg * 2 + c) * 20;
    #pragma unroll
    for (int k = 0; k < 20; k++) mj[c][k] = src[k];
  }
  float acc[2] = {0.f, 0.f};
  for (int ii = 0; ii < 16; ii++) {
    int i = ihalf * 16 + ii;
    const float4* m4 = (const float4*)(Ml + (size_t)i * 20);
    float mi[20];
    *(float4*)(mi + 0)  = m4[0]; *(float4*)(mi + 4)  = m4[1];
    *(float4*)(mi + 8)  = m4[2]; *(float4*)(mi + 12) = m4[3];
    *(float4*)(mi + 16) = m4[4];
    #pragma unroll
    for (int c = 0; c < 2; c++) {
      float norm = 0.f;
      #pragma unroll
      for (int k = 0; k < 20; k++) norm += fabsf(mi[k] - mj[c][k]);
      acc[c] += __expf(-norm);
    }
  }
  #pragma unroll
  for (int c = 0; c < 2; c++) parts[ihalf * 128 + jg * 2 + c] = acc[c];
  __syncthreads();
  if (t < 128) {
    float s = 0.f;
    #pragma unroll
    for (int ih = 0; ih < 8; ih++) s += parts[ih * 128 + t];
    feat[(size_t)t * 1536 + 1024 + o] = s - 1.0f;   // subtract self-term
  }
}

// ---------------------------------------------------------------------------
// final: out[r] = feat[r,:] . Wc + bc
// ---------------------------------------------------------------------------
__global__ __launch_bounds__(256) void final_dot(
    const float* __restrict__ feat, const float* __restrict__ Wc,
    const float* __restrict__ bc, float* __restrict__ out)
{
  __shared__ float red[4];
  const int t = threadIdx.x, r = blockIdx.x;
  float s = 0.f;
  for (int c = t; c < 1536; c += 256) s += feat[(size_t)r * 1536 + c] * Wc[c];
  for (int off = 32; off > 0; off >>= 1) s += __shfl_down(s, off);
  if ((t & 63) == 0) red[t >> 6] = s;
  __syncthreads();
  if (t == 0) out[r] = red[0] + red[1] + red[2] + red[3] + bc[0];
}

// ---------------------------------------------------------------------------
extern "C" void kernel_launch(void* const* d_in, const int* in_sizes, int n_in,
                              void* d_out, int out_size, void* d_ws, size_t ws_size,
                              hipStream_t stream)
{
  const float* X  = (const float*)d_in[0];
  const float* W1 = (const float*)d_in[1];
  const float* b1 = (const float*)d_in[2];
  const float* W2 = (const float*)d_in[3];
  const float* b2 = (const float*)d_in[4];
  const float* W3 = (const float*)d_in[5];
  const float* b3 = (const float*)d_in[6];
  const float* T  = (const float*)d_in[7];
  const float* Wc = (const float*)d_in[8];
  const float* bc = (const float*)d_in[9];

  char* ws = (char*)d_ws;
  float*          P    = (float*)ws;                  // fp32 partials (<= 8.4MB)
  unsigned short* accB = (unsigned short*)ws;         // bf16[4][128][10240] (after ep3)
  float*          h1   = (float*)(ws + 10485760);
  float*          h2   = (float*)(ws + 11534336);
  unsigned short* h3b  = (unsigned short*)(ws + 12058624);
  float*          feat = (float*)(ws + 12320768);
  float*          out  = (float*)d_out;

  // layer 1: [128,2048] = lrelu(X @ W1 + b1)   K=2048, S=8
  gemm_f32<<<dim3(64, 8), 256, 0, stream>>>(X, W1, P, 2048, 2048, 256);
  reduce_ep<<<512, 128, 0, stream>>>(P, b1, h1, nullptr, 2048, 8, 2048);
  // layer 2: [128,1024] = lrelu(h1 @ W2 + b2)  K=2048, S=16
  gemm_f32<<<dim3(32, 16), 256, 0, stream>>>(h1, W2, P, 2048, 1024, 128);
  reduce_ep<<<256, 128, 0, stream>>>(P, b2, h2, nullptr, 1024, 16, 1024);
  // layer 3: [128,1024] = lrelu(h2 @ W3 + b3)  K=1024, S=8 -> feat[:, :1024] + bf16
  gemm_f32<<<dim3(32, 8), 256, 0, stream>>>(h2, W3, P, 1024, 1024, 128);
  reduce_ep<<<256, 128, 0, stream>>>(P, b3, feat, h3b, 1024, 8, 1536);
  // M = h3 @ T  (bf16 MFMA, K-split 4 into bf16 accB)
  gemm4_mfma<<<dim3(160, 4), 256, 0, stream>>>(h3b, T, accB);
  // minibatch discrimination -> feat[:, 1024:]
  pairwise<<<512, 512, 0, stream>>>(accB, feat);
  // out = feat @ Wc + bc
  final_dot<<<128, 256, 0, stream>>>(feat, Wc, bc, out);
}